// Round 1
// baseline (182.617 us; speedup 1.0000x reference)
//
#include <hip/hip_runtime.h>
#include <math.h>

#define B 256
#define F 32
#define L 4096
#define NT 256
#define TWO_PI 6.28318530717958647692f

// LDS padding: +1 float2 per 16 -> conflict-free for strides 1/16/256 (measured 0 conflicts)
__device__ __forceinline__ int pidx(int i) { return i + (i >> 4); }

// reverse the 3 base-16 digits of i in [0,4096)
__device__ __forceinline__ int rev3(int i) {
    return ((i & 15) << 8) | (i & 0xF0) | (i >> 8);
}

__device__ __forceinline__ float2 cmul(float2 a, float2 b) {
    return make_float2(a.x * b.x - a.y * b.y, a.x * b.y + a.y * b.x);
}
__device__ __forceinline__ float2 cmulc(float2 a, float cr, float ci) {
    return make_float2(a.x * cr - a.y * ci, a.x * ci + a.y * cr);
}

// radix-4 butterfly, SGN=-1 forward, +1 inverse
template<int SGN>
__device__ __forceinline__ void dft4(float2& a, float2& b, float2& c, float2& d) {
    const float s = (float)SGN;
    float2 t0 = make_float2(a.x + c.x, a.y + c.y);
    float2 t1 = make_float2(a.x - c.x, a.y - c.y);
    float2 t2 = make_float2(b.x + d.x, b.y + d.y);
    float2 t3 = make_float2(b.x - d.x, b.y - d.y);
    float2 it3 = make_float2(-s * t3.y, s * t3.x);   // SGN*i*t3
    a = make_float2(t0.x + t2.x, t0.y + t2.y);
    c = make_float2(t0.x - t2.x, t0.y - t2.y);
    b = make_float2(t1.x + it3.x, t1.y + it3.y);
    d = make_float2(t1.x - it3.x, t1.y - it3.y);
}

// 16-point DFT in registers: v[p] = sum_q v_in[q] * exp(SGN*2pi*i*p*q/16)
template<int SGN>
__device__ __forceinline__ void dft16(float2 v[16]) {
    const float s = (float)SGN;
    const float C1 = 0.92387953251128675613f;   // cos(pi/8)
    const float S1 = 0.38268343236508977173f;   // sin(pi/8)
    const float C2 = 0.70710678118654752440f;   // cos(pi/4)
    #pragma unroll
    for (int c = 0; c < 4; ++c) dft4<SGN>(v[c], v[c + 4], v[c + 8], v[c + 12]);
    v[5]  = cmulc(v[5],  C1,  s * S1);              // W^1
    v[6]  = cmulc(v[6],  C2,  s * C2);              // W^2
    v[7]  = cmulc(v[7],  S1,  s * C1);              // W^3
    v[9]  = cmulc(v[9],  C2,  s * C2);              // W^2
    v[10] = make_float2(-s * v[10].y, s * v[10].x); // W^4 = SGN*i
    v[11] = cmulc(v[11], -C2, s * C2);              // W^6
    v[13] = cmulc(v[13], S1,  s * C1);              // W^3
    v[14] = cmulc(v[14], -C2, s * C2);              // W^6
    v[15] = cmulc(v[15], -C1, -s * S1);             // W^9
    float2 o[16];
    #pragma unroll
    for (int m = 0; m < 4; ++m) {
        float2 a = v[4*m], b = v[4*m+1], c = v[4*m+2], d = v[4*m+3];
        dft4<SGN>(a, b, c, d);
        o[m] = a; o[m+4] = b; o[m+8] = c; o[m+12] = d;
    }
    #pragma unroll
    for (int i = 0; i < 16; ++i) v[i] = o[i];
}

// v[q] *= w1^q for q=1..15 (recursive powers; err ~15 ulp, << tolerance)
__device__ __forceinline__ void twiddle_pow(float2 v[16], float2 w1) {
    float2 w = w1;
    #pragma unroll
    for (int q = 1; q < 16; ++q) {
        v[q] = cmul(v[q], w);
        w = cmul(w, w1);
    }
}

// per-thread twiddle generators (replaces the old LDS twp/T1 tables):
// w1 = exp(SGN*i*2pi*t/L), u1 = exp(SGN*i*2pi*(t&15)/256)
template<int SGN>
__device__ __forceinline__ void gen_tw(int t, float2& w1, float2& u1) {
    float sv, cv;
    sincosf((float)SGN * (TWO_PI / (float)L) * (float)t, &sv, &cv);
    w1 = make_float2(cv, sv);
    sincosf((float)SGN * (TWO_PI / 256.0f) * (float)(t & 15), &sv, &cv);
    u1 = make_float2(cv, sv);
}

// Forward DIF FFT, ONE barrier. Input v[q] = data[t + 256*q] (natural order).
// Output: v[r] = X(rev3(16*t + r)) (digit-reversed / scrambled).
// Exchange 2 (write base+16p / read 16t+q) is intra-wave: writer threads of
// the raw indices read by thread t are 16*(t>>4)+q, all inside t's wave64,
// so only a same-wave lgkmcnt wait (compiler-inserted) is needed, no barrier.
__device__ __forceinline__ void fft_dif_fwd(float2 v[16], float2* lds, int t) {
    float2 w1, u1;
    gen_tw<-1>(t, w1, u1);
    dft16<-1>(v);
    twiddle_pow(v, w1);
    #pragma unroll
    for (int p = 0; p < 16; ++p) lds[pidx(t + 256 * p)] = v[p];
    __syncthreads();                       // exchange 1 is cross-wave
    const int base = (t >> 4) * 256 + (t & 15);
    #pragma unroll
    for (int q = 0; q < 16; ++q) v[q] = lds[pidx(base + 16 * q)];
    dft16<-1>(v);
    twiddle_pow(v, u1);                    // == old T1 row (t&15), powers of u1
    #pragma unroll
    for (int p = 0; p < 16; ++p) lds[pidx(base + 16 * p)] = v[p];
    // exchange 2: intra-wave, no barrier
    #pragma unroll
    for (int q = 0; q < 16; ++q) v[q] = lds[pidx(16 * t + q)];
    dft16<-1>(v);
}

// ---------------- Kernel 1: fused prep (F + B/2 = 160 blocks, one round) -----
// Blocks [0,F): per-filter softmax + atom + forward FFT -> Anat[f] (natural).
// Blocks [F,..): x rows PACKED IN PAIRS (x real -> z = x0 + i*x1, one complex
// FFT per pair, half the x-FFT work) -> Znat[m] (natural order, scrambled idx).
__global__ void __launch_bounds__(NT) prep_kernel(const float* __restrict__ x,
                                                  const float* __restrict__ wp,
                                                  const float* __restrict__ fp,
                                                  float2* __restrict__ Znat,
                                                  float2* __restrict__ Anat) {
    __shared__ float2 lds[L + (L >> 4)];
    __shared__ float red[4];
    const int t = threadIdx.x;
    float2 v[16];

    if (blockIdx.x < F) {
        const int f = blockIdx.x;
        const float* row = wp + (size_t)f * L;
        float rv[16];
        #pragma unroll
        for (int c = 0; c < 16; ++c) rv[c] = row[t + 256 * c];
        float m = -INFINITY;
        #pragma unroll
        for (int c = 0; c < 16; ++c) m = fmaxf(m, rv[c]);
        #pragma unroll
        for (int off = 32; off; off >>= 1) m = fmaxf(m, __shfl_down(m, off));
        if ((t & 63) == 0) red[t >> 6] = m;
        __syncthreads();
        m = fmaxf(fmaxf(red[0], red[1]), fmaxf(red[2], red[3]));
        __syncthreads();
        float s = 0.0f;
        #pragma unroll
        for (int c = 0; c < 16; ++c) { rv[c] = expf(rv[c] - m); s += rv[c]; }
        #pragma unroll
        for (int off = 32; off; off >>= 1) s += __shfl_down(s, off);
        if ((t & 63) == 0) red[t >> 6] = s;
        __syncthreads();
        s = red[0] + red[1] + red[2] + red[3];
        const float inv = 1.0f / s;
        const float fr = 0.5f / (1.0f + expf(-fp[f]));
        const float w0 = -TWO_PI * fr;
        #pragma unroll
        for (int c = 0; c < 16; ++c) {
            const int n = t + 256 * c;
            const float e = rv[c] * inv;
            float sv, cv;
            sincosf(w0 * (float)n, &sv, &cv);
            v[c] = make_float2(e * cv, e * sv);
        }
        fft_dif_fwd(v, lds, t);
        float2* an = Anat + (size_t)f * L;
        #pragma unroll
        for (int r = 0; r < 16; ++r) an[rev3(16 * t + r)] = v[r];
    } else {
        const int m = blockIdx.x - F;              // x-row pair index
        const float* r0 = x + (size_t)(2 * m) * L;
        const float* r1 = r0 + L;
        #pragma unroll
        for (int q = 0; q < 16; ++q)
            v[q] = make_float2(r0[t + 256 * q], r1[t + 256 * q]);
        fft_dif_fwd(v, lds, t);
        float2* zn = Znat + (size_t)m * L;
        #pragma unroll
        for (int r = 0; r < 16; ++r) zn[rev3(16 * t + r)] = v[r];
    }
}

// ---------------- Kernel 2: Hermitian pairing/unpacking (F/2 + B/2 = 144) ----
// Blocks [0,F/2): C_j(k) = (G2j(k) + i*G2j1(k))/L, G_f(k) = (conj(Af(k)) + Af(L-k))/2.
//   Cs[j][i] = C_j(rev3(i)) so corr can read contiguously.
// Blocks [F/2,..): unpack packed x spectra: Z = fft(x0 + i*x1) ->
//   X0(k) = (Z(k)+conj(Z(L-k)))/2,  X1(k) = (Z(k)-conj(Z(L-k)))/(2i).
//   Xs[b][i] = X_b(rev3(i)) (scrambled, contiguous float4 for corr).
__global__ void __launch_bounds__(NT) pair_kernel(const float2* __restrict__ Anat,
                                                  const float2* __restrict__ Znat,
                                                  float2* __restrict__ Cs,
                                                  float2* __restrict__ Xs) {
    const int t = threadIdx.x;
    if (blockIdx.x < (F / 2)) {
        const int j = blockIdx.x;
        const float2* a0 = Anat + (size_t)(2 * j) * L;
        const float2* a1 = a0 + L;
        const float sc = 0.5f / (float)L;
        float2* co = Cs + (size_t)j * L;
        #pragma unroll
        for (int c = 0; c < 16; ++c) {
            const int i = t + 256 * c;
            const int k = rev3(i);
            const int km = (L - k) & (L - 1);
            const float2 a0k = a0[k], a0m = a0[km];
            const float2 a1k = a1[k], a1m = a1[km];
            const float g0r = a0k.x + a0m.x, g0i = a0m.y - a0k.y;   // 2*G_{2j}(k)
            const float g1r = a1k.x + a1m.x, g1i = a1m.y - a1k.y;   // 2*G_{2j+1}(k)
            co[i] = make_float2((g0r - g1i) * sc, (g0i + g1r) * sc);
        }
    } else {
        const int m = blockIdx.x - (F / 2);
        const float2* z = Znat + (size_t)m * L;
        float2* o0 = Xs + (size_t)(2 * m) * L;
        float2* o1 = o0 + L;
        #pragma unroll
        for (int c = 0; c < 16; ++c) {
            const int i = t + 256 * c;
            const int k = rev3(i);
            const int km = (L - k) & (L - 1);
            const float2 zk = z[k], zm = z[km];
            o0[i] = make_float2(0.5f * (zk.x + zm.x), 0.5f * (zk.y - zm.y));
            o1[i] = make_float2(0.5f * (zk.y + zm.y), 0.5f * (zm.x - zk.x));
        }
    }
}

// ---------------- Kernel 3: product + inverse DIT FFT (4096 blocks) ----------
// One FFT per block; stores only at block end (no barrier-after-store drain).
// __launch_bounds__(256,4): cap VGPR<=128 so LDS (34.8 KB now) is the binding
// limit -> 4 blocks/CU, 4096 blocks = exactly 4 full rounds.
// XCD swizzle: blk%8 == b%8 so each XCD's Xs working set is 32 rows (1 MB, L2-resident).
// Changes vs prev: twiddles in registers (no LDS tables, -4.4 KB), and the
// stage0->stage1 exchange is intra-wave -> ONE barrier instead of two.
__global__ void __launch_bounds__(NT, 4) corr_kernel(const float2* __restrict__ Xs,
                                                     const float2* __restrict__ Cs,
                                                     float* __restrict__ out) {
    __shared__ float2 lds[L + (L >> 4)];
    const int blk = blockIdx.x;                    // [0, 4096)
    const int jf = (blk >> 3) & 15;                // filter pair
    const int b = ((blk >> 7) << 3) | (blk & 7);   // x row, blk%8 == b%8
    const int t = threadIdx.x;

    // issue global loads first so they overlap the sincosf twiddle generation
    const float4* x4 = (const float4*)(Xs + (size_t)b * L + 16 * t);
    const float4* c4 = (const float4*)(Cs + (size_t)jf * L + 16 * t);
    float4 xa[8], ca[8];
    #pragma unroll
    for (int h = 0; h < 8; ++h) { xa[h] = x4[h]; ca[h] = c4[h]; }

    float2 w1, u1;
    gen_tw<1>(t, w1, u1);

    // DIT stage 0 (span 16): product, dft16, no twiddle
    float2 v[16];
    #pragma unroll
    for (int h = 0; h < 8; ++h) {
        v[2*h]   = cmul(make_float2(xa[h].x, xa[h].y), make_float2(ca[h].x, ca[h].y));
        v[2*h+1] = cmul(make_float2(xa[h].z, xa[h].w), make_float2(ca[h].z, ca[h].w));
    }
    dft16<1>(v);
    #pragma unroll
    for (int r = 0; r < 16; ++r) lds[pidx(16 * t + r)] = v[r];
    // stage0->stage1 exchange is intra-wave (writers 16*(t>>4)+q are in this
    // wave); same-wave LDS ordering via compiler lgkmcnt — no barrier.
    // DIT stage 1 (span 256)
    const int base = (t >> 4) * 256 + (t & 15);
    #pragma unroll
    for (int q = 0; q < 16; ++q) v[q] = lds[pidx(base + 16 * q)];
    twiddle_pow(v, u1);                            // == old T1 row (t&15)
    dft16<1>(v);
    #pragma unroll
    for (int r = 0; r < 16; ++r) lds[pidx(base + 16 * r)] = v[r];
    __syncthreads();                               // stage1->stage2 is cross-wave
    // DIT stage 2 (span 4096): outputs straight to global, natural order
    #pragma unroll
    for (int q = 0; q < 16; ++q) v[q] = lds[pidx(t + 256 * q)];
    twiddle_pow(v, w1);
    dft16<1>(v);
    float* o0 = out + ((size_t)b * F + 2 * jf) * L;
    float* o1 = o0 + L;
    #pragma unroll
    for (int r = 0; r < 16; ++r) {
        __builtin_nontemporal_store(v[r].x, o0 + t + 256 * r);
        __builtin_nontemporal_store(v[r].y, o1 + t + 256 * r);
    }
}

extern "C" void kernel_launch(void* const* d_in, const int* in_sizes, int n_in,
                              void* d_out, int out_size, void* d_ws, size_t ws_size,
                              hipStream_t stream) {
    (void)in_sizes; (void)n_in; (void)out_size; (void)ws_size;
    const float* x  = (const float*)d_in[0];   // [B, L]
    const float* wp = (const float*)d_in[1];   // [F, L]
    const float* fp = (const float*)d_in[2];   // [1, F]
    float* out = (float*)d_out;                // [B, F, L]

    float2* Xs   = (float2*)d_ws;              // B*L complex (scrambled spectra)
    float2* Cs   = Xs + (size_t)B * L;         // (F/2)*L complex (paired filters)
    float2* Anat = Cs + (size_t)(F / 2) * L;   // F*L complex (natural atom spectra)
    float2* Znat = Anat + (size_t)F * L;       // (B/2)*L complex (packed x spectra)

    prep_kernel<<<dim3(F + B / 2), dim3(NT), 0, stream>>>(x, wp, fp, Znat, Anat);
    pair_kernel<<<dim3(F / 2 + B / 2), dim3(NT), 0, stream>>>(Anat, Znat, Cs, Xs);
    corr_kernel<<<dim3(B * F / 2), dim3(NT), 0, stream>>>(Xs, Cs, out);
}

// Round 2
// 181.222 us; speedup vs baseline: 1.0077x; 1.0077x over previous
//
#include <hip/hip_runtime.h>
#include <math.h>

#define B 256
#define F 32
#define L 4096
#define NT 256
#define TWO_PI 6.28318530717958647692f

// LDS padding for FFT workspace: +1 float2 per 16 -> conflict-free for strides 1/16/256
__device__ __forceinline__ int pidx(int i) { return i + (i >> 4); }

// reverse the 3 base-16 digits of i in [0,4096)
__device__ __forceinline__ int rev3(int i) {
    return ((i & 15) << 8) | (i & 0xF0) | (i >> 8);
}

// XOR swizzle for natural-order spectrum buffers in LDS: mixes bits 4-7 and
// 8-11 into the bank bits so both the rev3 scatter (varies bits 4-11 per lane)
// and the natural gather (varies bits 4-11 per lane) are <=4-way. Bijective.
__device__ __forceinline__ int sw(int a) {
    return a ^ ((a >> 4) & 15) ^ ((a >> 8) & 15);
}

__device__ __forceinline__ float2 cmul(float2 a, float2 b) {
    return make_float2(a.x * b.x - a.y * b.y, a.x * b.y + a.y * b.x);
}
__device__ __forceinline__ float2 cmulc(float2 a, float cr, float ci) {
    return make_float2(a.x * cr - a.y * ci, a.x * ci + a.y * cr);
}

// radix-4 butterfly, SGN=-1 forward, +1 inverse
template<int SGN>
__device__ __forceinline__ void dft4(float2& a, float2& b, float2& c, float2& d) {
    const float s = (float)SGN;
    float2 t0 = make_float2(a.x + c.x, a.y + c.y);
    float2 t1 = make_float2(a.x - c.x, a.y - c.y);
    float2 t2 = make_float2(b.x + d.x, b.y + d.y);
    float2 t3 = make_float2(b.x - d.x, b.y - d.y);
    float2 it3 = make_float2(-s * t3.y, s * t3.x);   // SGN*i*t3
    a = make_float2(t0.x + t2.x, t0.y + t2.y);
    c = make_float2(t0.x - t2.x, t0.y - t2.y);
    b = make_float2(t1.x + it3.x, t1.y + it3.y);
    d = make_float2(t1.x - it3.x, t1.y - it3.y);
}

// 16-point DFT in registers
template<int SGN>
__device__ __forceinline__ void dft16(float2 v[16]) {
    const float s = (float)SGN;
    const float C1 = 0.92387953251128675613f;   // cos(pi/8)
    const float S1 = 0.38268343236508977173f;   // sin(pi/8)
    const float C2 = 0.70710678118654752440f;   // cos(pi/4)
    #pragma unroll
    for (int c = 0; c < 4; ++c) dft4<SGN>(v[c], v[c + 4], v[c + 8], v[c + 12]);
    v[5]  = cmulc(v[5],  C1,  s * S1);              // W^1
    v[6]  = cmulc(v[6],  C2,  s * C2);              // W^2
    v[7]  = cmulc(v[7],  S1,  s * C1);              // W^3
    v[9]  = cmulc(v[9],  C2,  s * C2);              // W^2
    v[10] = make_float2(-s * v[10].y, s * v[10].x); // W^4 = SGN*i
    v[11] = cmulc(v[11], -C2, s * C2);              // W^6
    v[13] = cmulc(v[13], S1,  s * C1);              // W^3
    v[14] = cmulc(v[14], -C2, s * C2);              // W^6
    v[15] = cmulc(v[15], -C1, -s * S1);             // W^9
    float2 o[16];
    #pragma unroll
    for (int m = 0; m < 4; ++m) {
        float2 a = v[4*m], b = v[4*m+1], c = v[4*m+2], d = v[4*m+3];
        dft4<SGN>(a, b, c, d);
        o[m] = a; o[m+4] = b; o[m+8] = c; o[m+12] = d;
    }
    #pragma unroll
    for (int i = 0; i < 16; ++i) v[i] = o[i];
}

// v[q] *= w1^q for q=1..15 (recursive powers; err ~15 ulp, << tolerance)
__device__ __forceinline__ void twiddle_pow(float2 v[16], float2 w1) {
    float2 w = w1;
    #pragma unroll
    for (int q = 1; q < 16; ++q) {
        v[q] = cmul(v[q], w);
        w = cmul(w, w1);
    }
}

// per-thread twiddle generators:
// w1 = exp(SGN*i*2pi*t/L), u1 = exp(SGN*i*2pi*(t&15)/256)
template<int SGN>
__device__ __forceinline__ void gen_tw(int t, float2& w1, float2& u1) {
    float sv, cv;
    sincosf((float)SGN * (TWO_PI / (float)L) * (float)t, &sv, &cv);
    w1 = make_float2(cv, sv);
    sincosf((float)SGN * (TWO_PI / 256.0f) * (float)(t & 15), &sv, &cv);
    u1 = make_float2(cv, sv);
}

// Forward DIF FFT, ONE barrier. Input v[q] = data[t + 256*q] (natural order).
// Output: v[r] = X(rev3(16*t + r)) (digit-reversed / scrambled).
// Exchange 2 (write base+16p / read 16t+q) is intra-wave (writers
// (t&~15)|q are in t's wave64) -> compiler lgkmcnt only, no barrier.
__device__ __forceinline__ void fft_dif_fwd(float2 v[16], float2* lds, int t) {
    float2 w1, u1;
    gen_tw<-1>(t, w1, u1);
    dft16<-1>(v);
    twiddle_pow(v, w1);
    #pragma unroll
    for (int p = 0; p < 16; ++p) lds[pidx(t + 256 * p)] = v[p];
    __syncthreads();                       // exchange 1 is cross-wave
    const int base = (t >> 4) * 256 + (t & 15);
    #pragma unroll
    for (int q = 0; q < 16; ++q) v[q] = lds[pidx(base + 16 * q)];
    dft16<-1>(v);
    twiddle_pow(v, u1);
    #pragma unroll
    for (int p = 0; p < 16; ++p) lds[pidx(base + 16 * p)] = v[p];
    // exchange 2: intra-wave, no barrier
    #pragma unroll
    for (int q = 0; q < 16; ++q) v[q] = lds[pidx(16 * t + q)];
    dft16<-1>(v);
}

// softmax(row) * exp(-i*2pi*fr*n) -> forward FFT, result scrambled in v.
// Block-uniform call (contains barriers).
__device__ __forceinline__ void atom_fft(const float* __restrict__ row, float fpv,
                                         float2 v[16], float2* lds, float* red, int t) {
    float rv[16];
    #pragma unroll
    for (int c = 0; c < 16; ++c) rv[c] = row[t + 256 * c];
    float m = -INFINITY;
    #pragma unroll
    for (int c = 0; c < 16; ++c) m = fmaxf(m, rv[c]);
    #pragma unroll
    for (int off = 32; off; off >>= 1) m = fmaxf(m, __shfl_down(m, off));
    if ((t & 63) == 0) red[t >> 6] = m;
    __syncthreads();
    m = fmaxf(fmaxf(red[0], red[1]), fmaxf(red[2], red[3]));
    __syncthreads();
    float s = 0.0f;
    #pragma unroll
    for (int c = 0; c < 16; ++c) { rv[c] = expf(rv[c] - m); s += rv[c]; }
    #pragma unroll
    for (int off = 32; off; off >>= 1) s += __shfl_down(s, off);
    if ((t & 63) == 0) red[t >> 6] = s;
    __syncthreads();
    s = red[0] + red[1] + red[2] + red[3];
    const float inv = 1.0f / s;
    const float fr = 0.5f / (1.0f + expf(-fpv));
    const float w0 = -TWO_PI * fr;
    #pragma unroll
    for (int c = 0; c < 16; ++c) {
        const int n = t + 256 * c;
        const float e = rv[c] * inv;
        float sv, cv;
        sincosf(w0 * (float)n, &sv, &cv);
        v[c] = make_float2(e * cv, e * sv);
    }
    __syncthreads();                 // all waves done with prior workspace use
    fft_dif_fwd(v, lds, t);
}

// ---------------- Kernel 1: fully fused prep (F/2 + B/2 = 144 blocks) --------
// Blocks [0,F/2): filter pair j -> two softmax+atom+FFTs staged in LDS,
//   Hermitian-combined into C_j, written scrambled-coalesced to Cs.
//   C_j(k) = (G2j(k) + i*G2j1(k))/L, G_f(k) = (conj(Af(k)) + Af(L-k))/2.
// Blocks [F/2,..): x rows packed in pairs (z = x0 + i*x1, one complex FFT per
//   pair), spectrum staged in LDS (natural order, XOR-swizzled), unpacked to
//   X0/X1 and written scrambled-coalesced to Xs. No Znat/Anat global traffic.
__global__ void __launch_bounds__(NT) prep_kernel(const float* __restrict__ x,
                                                  const float* __restrict__ wp,
                                                  const float* __restrict__ fp,
                                                  float2* __restrict__ Cs,
                                                  float2* __restrict__ Xs) {
    __shared__ float2 lds[L + (L >> 4)];   // FFT workspace (34.8 KB)
    __shared__ float2 specA[L];            // natural-order spectrum (32 KB)
    __shared__ float2 specB[L];            // second spectrum (filter pairs)
    __shared__ float red[4];
    const int t = threadIdx.x;
    float2 v[16];

    if (blockIdx.x < (F / 2)) {
        const int j = blockIdx.x;
        atom_fft(wp + (size_t)(2 * j) * L, fp[2 * j], v, lds, red, t);
        #pragma unroll
        for (int r = 0; r < 16; ++r) specA[sw(rev3(16 * t + r))] = v[r];
        __syncthreads();                 // specA done; workspace free for FFT-B
        atom_fft(wp + (size_t)(2 * j + 1) * L, fp[2 * j + 1], v, lds, red, t);
        #pragma unroll
        for (int r = 0; r < 16; ++r) specB[sw(rev3(16 * t + r))] = v[r];
        __syncthreads();
        const float sc = 0.5f / (float)L;
        float2* co = Cs + (size_t)j * L;
        #pragma unroll
        for (int c = 0; c < 16; ++c) {
            const int i = t + 256 * c;
            const int k = rev3(i);
            const int km = (L - k) & (L - 1);
            const float2 a0k = specA[sw(k)], a0m = specA[sw(km)];
            const float2 a1k = specB[sw(k)], a1m = specB[sw(km)];
            const float g0r = a0k.x + a0m.x, g0i = a0m.y - a0k.y;   // 2*G_{2j}(k)
            const float g1r = a1k.x + a1m.x, g1i = a1m.y - a1k.y;   // 2*G_{2j+1}(k)
            co[i] = make_float2((g0r - g1i) * sc, (g0i + g1r) * sc);
        }
    } else {
        const int m = blockIdx.x - (F / 2);        // x-row pair index
        const float* r0 = x + (size_t)(2 * m) * L;
        const float* r1 = r0 + L;
        #pragma unroll
        for (int q = 0; q < 16; ++q)
            v[q] = make_float2(r0[t + 256 * q], r1[t + 256 * q]);
        __syncthreads();
        fft_dif_fwd(v, lds, t);
        #pragma unroll
        for (int r = 0; r < 16; ++r) specA[sw(rev3(16 * t + r))] = v[r];
        __syncthreads();
        // unpack Z = fft(x0 + i*x1): X0(k) = (Z(k)+conj(Z(L-k)))/2,
        //                            X1(k) = (Z(k)-conj(Z(L-k)))/(2i)
        float2* o0 = Xs + (size_t)(2 * m) * L;
        float2* o1 = o0 + L;
        #pragma unroll
        for (int c = 0; c < 16; ++c) {
            const int i = t + 256 * c;
            const int k = rev3(i);
            const int km = (L - k) & (L - 1);
            const float2 zk = specA[sw(k)], zm = specA[sw(km)];
            o0[i] = make_float2(0.5f * (zk.x + zm.x), 0.5f * (zk.y - zm.y));
            o1[i] = make_float2(0.5f * (zk.y + zm.y), 0.5f * (zm.x - zk.x));
        }
    }
}

// ---------------- Kernel 2: product + inverse DIT FFT (4096 blocks) ----------
// __launch_bounds__(256,4): LDS 37 KB is the binding limit -> 4 blocks/CU,
// 4096 blocks = exactly 4 full rounds.
// XCD swizzle: blk%8 == b%8 so each XCD's Xs working set is 32 rows (L2-resident).
// Stage-1 twiddles from the conflict-free stride-17 T1 table (cheaper than the
// register power-chain: -15 cmul/thread); T1 built before the early barrier,
// which also serves as the vmcnt drain for the just-issued global loads.
// Stage0->1 exchange stays intra-wave (no barrier).
__global__ void __launch_bounds__(NT, 4) corr_kernel(const float2* __restrict__ Xs,
                                                     const float2* __restrict__ Cs,
                                                     float* __restrict__ out) {
    __shared__ float2 lds[L + (L >> 4)];
    __shared__ float2 T1[272];
    const int blk = blockIdx.x;                    // [0, 4096)
    const int jf = (blk >> 3) & 15;                // filter pair
    const int b = ((blk >> 7) << 3) | (blk & 7);   // x row, blk%8 == b%8
    const int t = threadIdx.x;

    // issue global loads first so they overlap the sincosf twiddle build
    const float4* x4 = (const float4*)(Xs + (size_t)b * L + 16 * t);
    const float4* c4 = (const float4*)(Cs + (size_t)jf * L + 16 * t);
    float4 xa[8], ca[8];
    #pragma unroll
    for (int h = 0; h < 8; ++h) { xa[h] = x4[h]; ca[h] = c4[h]; }

    float sv, cv;
    sincosf((TWO_PI / 256.0f) * (float)((t >> 4) * (t & 15)), &sv, &cv);
    T1[17 * (t >> 4) + (t & 15)] = make_float2(cv, sv);   // exp(+i*2pi*a*b/256)
    float2 w1;
    sincosf((TWO_PI / (float)L) * (float)t, &sv, &cv);
    w1 = make_float2(cv, sv);                             // exp(+i*2pi*t/L)
    __syncthreads();   // T1 visible; implicit vmcnt drain (loads needed next)

    // DIT stage 0 (span 16): product, dft16, no twiddle
    float2 v[16];
    #pragma unroll
    for (int h = 0; h < 8; ++h) {
        v[2*h]   = cmul(make_float2(xa[h].x, xa[h].y), make_float2(ca[h].x, ca[h].y));
        v[2*h+1] = cmul(make_float2(xa[h].z, xa[h].w), make_float2(ca[h].z, ca[h].w));
    }
    dft16<1>(v);
    #pragma unroll
    for (int r = 0; r < 16; ++r) lds[pidx(16 * t + r)] = v[r];
    // stage0->stage1 exchange is intra-wave — no barrier
    const int base = (t >> 4) * 256 + (t & 15);
    #pragma unroll
    for (int q = 0; q < 16; ++q) v[q] = lds[pidx(base + 16 * q)];
    {
        const float2* Tr = T1 + 17 * (t & 15);
        #pragma unroll
        for (int q = 1; q < 16; ++q) v[q] = cmul(v[q], Tr[q]);
    }
    dft16<1>(v);
    #pragma unroll
    for (int r = 0; r < 16; ++r) lds[pidx(base + 16 * r)] = v[r];
    __syncthreads();                               // stage1->stage2 is cross-wave
    // DIT stage 2 (span 4096): outputs straight to global, natural order
    #pragma unroll
    for (int q = 0; q < 16; ++q) v[q] = lds[pidx(t + 256 * q)];
    twiddle_pow(v, w1);
    dft16<1>(v);
    float* o0 = out + ((size_t)b * F + 2 * jf) * L;
    float* o1 = o0 + L;
    #pragma unroll
    for (int r = 0; r < 16; ++r) {
        __builtin_nontemporal_store(v[r].x, o0 + t + 256 * r);
        __builtin_nontemporal_store(v[r].y, o1 + t + 256 * r);
    }
}

extern "C" void kernel_launch(void* const* d_in, const int* in_sizes, int n_in,
                              void* d_out, int out_size, void* d_ws, size_t ws_size,
                              hipStream_t stream) {
    (void)in_sizes; (void)n_in; (void)out_size; (void)ws_size;
    const float* x  = (const float*)d_in[0];   // [B, L]
    const float* wp = (const float*)d_in[1];   // [F, L]
    const float* fp = (const float*)d_in[2];   // [1, F]
    float* out = (float*)d_out;                // [B, F, L]

    float2* Xs = (float2*)d_ws;                // B*L complex (scrambled spectra)
    float2* Cs = Xs + (size_t)B * L;           // (F/2)*L complex (paired filters)

    prep_kernel<<<dim3(F / 2 + B / 2), dim3(NT), 0, stream>>>(x, wp, fp, Cs, Xs);
    corr_kernel<<<dim3(B * F / 2), dim3(NT), 0, stream>>>(Xs, Cs, out);
}